// Round 6
// baseline (366.880 us; speedup 1.0000x reference)
//
#include <hip/hip_runtime.h>

// Problem: 500 GD steps on a 2-conv model, loss = ||FFT(y)-FFT(yhat)||^2.
// Parseval => loss = 256 * sum (y - yhat)^2 ; mean over batch 1024 => 2c = 0.5.
// yhat[n,w] = beff + sum_{i=(r,a)} A[i] * xpad[n, r, w+a-10],
//   A[r,a] = sum_h k2[h]*k1[r-h+1,a],  beff = b2 + b1*(k2[0]+k2[1]+k2[2]).
// Sufficient stats: XX[63][63], XY[63], Sx[63], Ysum. Train on those; then apply.
//
// k_train R6: R3-R5 rocprof proved the allocator will NOT keep a 64-float
// per-lane matrix row live across the loop (VGPR_Count 68/68/48, FETCH_SIZE
// ~11-14MB/dispatch = full spill-reload each iteration). So: matrix goes to
// LDS (16KB), XOR-swizzled so the per-iter ds_read_b128 pattern is
// bank-conflict-optimal (8 words/bank). z broadcast stays v_readlane (VALU
// pipe). Matrix is read-only in the loop -> ZERO barriers in the 500-iter
// loop. A per-iter asm pin on the swizzle operand defeats LICM so the LDS
// reads cannot be hoisted (which would recreate the spill).
// k_reduce now writes the AUGMENTED matrix M=[[XX,Sx],[Sx^T,NW]] (row stride
// 64, float4-aligned) + RHS=[XY,Ysum] directly.

#define NB1 4              // batch rows per k_stats block
#define NBLK 256           // 1024 / NB1
#define PSTRIDE 4096       // 3969 XX + 63 XY + 63 Sx + 1 Ysum = 4096
#define ST_OFF (NBLK * PSTRIDE)     // 1048576 floats: partials end / M begins
#define RHS_OFF (ST_OFF + 4096)     // M is 64*64
#define AF_OFF (RHS_OFF + 64)
// fallback (atomic) layout: ST0 at 0 (4096), M at 4096, RHS at 8192, AF at 8256
#define FB_M 4096
#define FB_RHS 8192
#define FB_AF 8256

// ---------------- stats kernel ----------------
template <int ATOMIC>
__global__ __launch_bounds__(256) void k_stats(const float* __restrict__ in,
                                               float* __restrict__ Pbase) {
    __shared__ float xs[NB1][3][276];   // zero-padded rows: u+10, u in [-10,265]
    __shared__ float ys[NB1][256];
    const int tid = threadIdx.x;
    const int n0 = blockIdx.x * NB1;

    float* xsf = &xs[0][0][0];
    for (int p = tid; p < NB1 * 3 * 276; p += 256) xsf[p] = 0.f;
    __syncthreads();
    for (int p = tid; p < NB1 * 4 * 256; p += 256) {
        int w = p & 255, h = (p >> 8) & 3, n = p >> 10;
        float v = in[((n0 + n) * 4 + h) * 256 + w];
        if (h == 0) ys[n][w] = v;
        else xs[n][h - 1][10 + w] = v;
    }
    __syncthreads();

    // rows: i = 4*ti + p (broadcast across the 16 lanes of a row);
    // cols: j = 16*q + tj  -> lanes read CONSECUTIVE words (bank-conflict-free)
    const int ti = tid >> 4, tj = tid & 15;
    const int i0 = ti * 4;
    int ir[4], ia[4], jr[4], ja[4];
#pragma unroll
    for (int p = 0; p < 4; ++p) {
        int i = i0 + p; if (i > 62) i = 62;
        ir[p] = i / 21; ia[p] = i % 21;
        int j = p * 16 + tj; if (j > 62) j = 62;
        jr[p] = j / 21; ja[p] = j % 21;
    }
    float acc[4][4] = {{0.f, 0.f, 0.f, 0.f}, {0.f, 0.f, 0.f, 0.f},
                       {0.f, 0.f, 0.f, 0.f}, {0.f, 0.f, 0.f, 0.f}};
    for (int n = 0; n < NB1; ++n) {
        const float* ba0 = &xs[n][ir[0]][ia[0]];
        const float* ba1 = &xs[n][ir[1]][ia[1]];
        const float* ba2 = &xs[n][ir[2]][ia[2]];
        const float* ba3 = &xs[n][ir[3]][ia[3]];
        const float* bb0 = &xs[n][jr[0]][ja[0]];
        const float* bb1 = &xs[n][jr[1]][ja[1]];
        const float* bb2 = &xs[n][jr[2]][ja[2]];
        const float* bb3 = &xs[n][jr[3]][ja[3]];
#pragma unroll 4
        for (int w = 0; w < 256; ++w) {
            float va0 = ba0[w], va1 = ba1[w], va2 = ba2[w], va3 = ba3[w];
            float vb0 = bb0[w], vb1 = bb1[w], vb2 = bb2[w], vb3 = bb3[w];
            acc[0][0] += va0 * vb0; acc[0][1] += va0 * vb1;
            acc[0][2] += va0 * vb2; acc[0][3] += va0 * vb3;
            acc[1][0] += va1 * vb0; acc[1][1] += va1 * vb1;
            acc[1][2] += va1 * vb2; acc[1][3] += va1 * vb3;
            acc[2][0] += va2 * vb0; acc[2][1] += va2 * vb1;
            acc[2][2] += va2 * vb2; acc[2][3] += va2 * vb3;
            acc[3][0] += va3 * vb0; acc[3][1] += va3 * vb1;
            acc[3][2] += va3 * vb2; acc[3][3] += va3 * vb3;
        }
    }
    float* Pb = ATOMIC ? Pbase : (Pbase + blockIdx.x * PSTRIDE);
#pragma unroll
    for (int p = 0; p < 4; ++p)
#pragma unroll
        for (int q = 0; q < 4; ++q) {
            int i = i0 + p, j = q * 16 + tj;   // raw (unclamped) indices
            if (i < 63 && j < 63) {
                if (ATOMIC) unsafeAtomicAdd(&Pb[i * 63 + j], acc[p][q]);
                else Pb[i * 63 + j] = acc[p][q];
            }
        }
    if (tid < 127) {
        float a2 = 0.f;
        int slot;
        if (tid < 63) {
            int r = tid / 21, a = tid % 21;
            for (int n = 0; n < NB1; ++n) {
                const float* xa = &xs[n][r][a];
                const float* yy = ys[n];
                float s = 0.f;
                for (int w = 0; w < 256; ++w) s += xa[w] * yy[w];
                a2 += s;
            }
            slot = 3969 + tid;
        } else if (tid < 126) {
            int e = tid - 63, r = e / 21, a = e % 21;
            for (int n = 0; n < NB1; ++n) {
                const float* xa = &xs[n][r][a];
                float s = 0.f;
                for (int w = 0; w < 256; ++w) s += xa[w];
                a2 += s;
            }
            slot = 4032 + e;
        } else {
            for (int n = 0; n < NB1; ++n) {
                const float* yy = ys[n];
                float s = 0.f;
                for (int w = 0; w < 256; ++w) s += yy[w];
                a2 += s;
            }
            slot = 4095;
        }
        if (ATOMIC) unsafeAtomicAdd(&Pb[slot], a2);
        else Pb[slot] = a2;
    }
}

// ------- deterministic reduction + scatter into augmented M / RHS -------
// M (64x64, row stride 64): rows 0..62 = [XX[i,:], Sx[i]], row 63 = [Sx, NW].
// RHS (64): [XY[0..62], Ysum].
template <int COUNT>
__global__ __launch_bounds__(256) void k_reduce(const float* __restrict__ P,
                                                float* __restrict__ M,
                                                float* __restrict__ RHS) {
    int e = blockIdx.x * 256 + threadIdx.x;  // 0..4095
    double s = 0.0;
    for (int b = 0; b < COUNT; ++b) s += (double)P[b * PSTRIDE + e];
    float f = (float)s;
    if (e < 3969) {
        int i = e / 63, j = e % 63;
        M[i * 64 + j] = f;
    } else if (e < 4032) {
        RHS[e - 3969] = f;                 // XY[i]
    } else if (e < 4095) {
        int i = e - 4032;                  // Sx[i]
        M[i * 64 + 63] = f;
        M[63 * 64 + i] = f;
    } else {
        RHS[63] = f;                       // Ysum
        M[63 * 64 + 63] = 262144.f;        // NW = 1024*256
    }
}

// ---------------- DPP helpers (VALU-pipe cross-lane) ----------------
template <int CTRL>
__device__ __forceinline__ float dpp_sum_step(float v) {
    int moved = __builtin_amdgcn_update_dpp(0, __float_as_int(v), CTRL, 0xf, 0xf, false);
    return v + __int_as_float(moved);
}
// full-wave (64) sum; returns total as a wave-uniform value (via lane 63)
__device__ __forceinline__ float wave_sum64(float v) {
    v = dpp_sum_step<0x111>(v);   // row_shr:1
    v = dpp_sum_step<0x112>(v);   // row_shr:2
    v = dpp_sum_step<0x114>(v);   // row_shr:4
    v = dpp_sum_step<0x118>(v);   // row_shr:8
    v = dpp_sum_step<0x142>(v);   // row_bcast:15
    v = dpp_sum_step<0x143>(v);   // row_bcast:31
    return __int_as_float(__builtin_amdgcn_readlane(__float_as_int(v), 63));
}
__device__ __forceinline__ float lane_bcast(float v, int lane) {
    return __int_as_float(__builtin_amdgcn_readlane(__float_as_int(v), lane));
}

// ---------------- training: 500 GD steps, one wave, matrix in LDS ------
__global__ __launch_bounds__(64) void k_train(const float* __restrict__ M,
                                              const float* __restrict__ RHS,
                                              const float* __restrict__ k1_in,
                                              const float* __restrict__ b1_in,
                                              const float* __restrict__ k2_in,
                                              const float* __restrict__ b2_in,
                                              float* __restrict__ AF) {
    // Row t in Ml[t][*]; logical float4 chunk j4 stored at physical j4^(t&15).
    // At fixed logical j4 the 64 lanes then hit all 32 banks at 8 words/bank
    // (optimal for ds_read_b128); unswizzled row-major would serialize ~16x.
    __shared__ float4 Ml[64][16];
    const int t = threadIdx.x;
    const int x = t & 15;

    const float4* Mrow = (const float4*)(M + t * 64);
#pragma unroll
    for (int j4 = 0; j4 < 16; ++j4) Ml[t][j4 ^ x] = Mrow[j4];
    float XYr = RHS[t];                    // XY[t] | Ysum (t==63)

    // validity masks for the replicated/shifted k1 state
    const bool m_own = (t < 63);             // lane owns k1[t]
    const bool mu    = (t < 42);             // k1[t+21] exists
    const bool md    = (t >= 21 && t < 63);  // k1[t-21] exists
    const bool mpp   = (t < 21);             // G[t+42] valid for k1u update
    const bool mmm   = (t >= 42);            // G[t-42] valid for k1d update

    // replicated state: k1v = k1[t], k1u = k1[t+21], k1d = k1[t-21] (masked 0)
    float k1v = m_own ? k1_in[t] : 0.f;
    float k1u = mu ? k1_in[t + 21] : 0.f;
    float k1d = md ? k1_in[t - 21] : 0.f;
    // scalars replicated in every lane (identical updates -> identical values)
    float k20 = k2_in[0], k21 = k2_in[1], k22 = k2_in[2];
    float b1 = b1_in[0], b2 = b2_in[0];

    __syncthreads();   // one-time: LDS matrix visible; loop itself barrier-free

    const float LRf = 1e-7f;

    for (int it = 0; it < 500; ++it) {
        // Defeat LICM: make the swizzle operand opaque each iteration so the
        // 16 LDS loads can't be hoisted out (which would respill to scratch).
        int xx = x;
        asm volatile("" : "+v"(xx));

        float S = k20 + k21 + k22;
        float beff = b2 + b1 * S;
        // A[t] = k20*k1[t+21] + k21*k1[t] + k22*k1[t-21]  (pure per-lane FMA)
        float A = k20 * k1u + k21 * k1v + k22 * k1d;
        float z = m_own ? A : beff;   // z[63] = beff

        // G_all = 0.5*(M.z - rhs): matrix row from LDS, z via readlane bcast
        float a0 = 0.f, a1 = 0.f, a2 = 0.f, a3 = 0.f;
        float a4 = 0.f, a5 = 0.f, a6 = 0.f, a7 = 0.f;
#pragma unroll
        for (int j4 = 0; j4 < 16; j4 += 2) {
            float4 mv0 = Ml[t][j4 ^ xx];
            float4 mv1 = Ml[t][(j4 + 1) ^ xx];
            a0 = fmaf(mv0.x, lane_bcast(z, 4 * j4 + 0), a0);
            a1 = fmaf(mv0.y, lane_bcast(z, 4 * j4 + 1), a1);
            a2 = fmaf(mv0.z, lane_bcast(z, 4 * j4 + 2), a2);
            a3 = fmaf(mv0.w, lane_bcast(z, 4 * j4 + 3), a3);
            a4 = fmaf(mv1.x, lane_bcast(z, 4 * j4 + 4), a4);
            a5 = fmaf(mv1.y, lane_bcast(z, 4 * j4 + 5), a5);
            a6 = fmaf(mv1.z, lane_bcast(z, 4 * j4 + 6), a6);
            a7 = fmaf(mv1.w, lane_bcast(z, 4 * j4 + 7), a7);
        }
        float dot = ((a0 + a1) + (a2 + a3)) + ((a4 + a5) + (a6 + a7));
        float Gall = 0.5f * (dot - XYr);

        float E = lane_bcast(Gall, 63);          // lane 63 of matvec is E
        float Gv = m_own ? Gall : 0.f;           // masked gradient vector

        // c-sums: lane-local products, DPP reductions (VALU pipe)
        float c0 = wave_sum64(k1u * Gv);
        float c1 = wave_sum64(k1v * Gv);
        float c2 = wave_sum64(k1d * Gv);

        // 4 parallel bpermutes for the stencil rows of G
        float Gp  = __shfl(Gv, t + 21);   // G[t+21] (valid if mu)
        float Gm  = __shfl(Gv, t - 21);   // G[t-21] (valid if t>=21)
        float Gpp = __shfl(Gv, t + 42);   // G[t+42] (valid if mpp)
        float Gmm = __shfl(Gv, t - 42);   // G[t-42] (valid if mmm)
        float Gp_m  = mu  ? Gp  : 0.f;
        float Gm_m  = (t >= 21) ? Gm : 0.f;
        float Gpp_m = mpp ? Gpp : 0.f;
        float Gmm_m = mmm ? Gmm : 0.f;

        // gradient stencils for the three k1 replicas
        float gk1v = k20 * Gm_m  + k21 * Gv   + k22 * Gp_m;   // at index t
        float gk1u = k20 * Gv    + k21 * Gp_m + k22 * Gpp_m;  // at index t+21
        float gk1d = k20 * Gmm_m + k21 * Gm_m + k22 * Gv;     // at index t-21

        // updates (all from pre-update values; scalar ones uniform per lane)
        float bE = b1 * E;
        k1v -= m_own ? LRf * gk1v : 0.f;
        k1u -= mu    ? LRf * gk1u : 0.f;
        k1d -= md    ? LRf * gk1d : 0.f;
        k20 -= LRf * (bE + c0);
        k21 -= LRf * (bE + c1);
        k22 -= LRf * (bE + c2);
        b1  -= LRf * (S * E);
        b2  -= LRf * E;
    }

    // emit final effective kernel
    float A = k20 * k1u + k21 * k1v + k22 * k1d;
    AF[t] = m_own ? A : (b2 + b1 * (k20 + k21 + k22));
}

// ---------------- apply: out = y - yhat(final params) ----------------
__global__ __launch_bounds__(256) void k_apply(const float* __restrict__ in,
                                               const float* __restrict__ AF,
                                               float* __restrict__ out) {
    __shared__ float xs[3][276];
    __shared__ float As[64];
    const int n = blockIdx.x, t = threadIdx.x;
    float* xsf = &xs[0][0];
    for (int p = t; p < 3 * 276; p += 256) xsf[p] = 0.f;
    if (t < 64) As[t] = AF[t];
    __syncthreads();
    for (int p = t; p < 3 * 256; p += 256) {
        int r = p >> 8, w = p & 255;
        xs[r][10 + w] = in[(n * 4 + 1 + r) * 256 + w];
    }
    __syncthreads();
    float s = As[63];  // beff
#pragma unroll
    for (int r = 0; r < 3; ++r)
#pragma unroll
        for (int a = 0; a < 21; ++a)
            s += As[r * 21 + a] * xs[r][t + a];
    out[n * 256 + t] = in[(n * 4) * 256 + t] - s;
}

extern "C" void kernel_launch(void* const* d_in, const int* in_sizes, int n_in,
                              void* d_out, int out_size, void* d_ws, size_t ws_size,
                              hipStream_t stream) {
    const float* in = (const float*)d_in[0];
    const float* k1 = (const float*)d_in[1];
    const float* b1 = (const float*)d_in[2];
    const float* k2 = (const float*)d_in[3];
    const float* b2 = (const float*)d_in[4];
    float* out = (float*)d_out;
    float* ws = (float*)d_ws;

    const size_t need = (size_t)(AF_OFF + 64) * sizeof(float);  // ~4.2 MiB
    if (ws_size >= need) {
        float* P   = ws;
        float* M   = ws + ST_OFF;
        float* RHS = ws + RHS_OFF;
        float* AF  = ws + AF_OFF;
        k_stats<0><<<NBLK, 256, 0, stream>>>(in, P);
        k_reduce<NBLK><<<16, 256, 0, stream>>>(P, M, RHS);
        k_train<<<1, 64, 0, stream>>>(M, RHS, k1, b1, k2, b2, AF);
        k_apply<<<1024, 256, 0, stream>>>(in, AF, out);
    } else {
        float* ST0 = ws;
        float* M   = ws + FB_M;
        float* RHS = ws + FB_RHS;
        float* AF  = ws + FB_AF;
        hipMemsetAsync(ST0, 0, PSTRIDE * sizeof(float), stream);
        k_stats<1><<<NBLK, 256, 0, stream>>>(in, ST0);
        k_reduce<1><<<16, 256, 0, stream>>>(ST0, M, RHS);
        k_train<<<1, 64, 0, stream>>>(M, RHS, k1, b1, k2, b2, AF);
        k_apply<<<1024, 256, 0, stream>>>(in, AF, out);
    }
}